// Round 1
// baseline (225.751 us; speedup 1.0000x reference)
//
#include <hip/hip_runtime.h>

// ---------------------------------------------------------------------------
// MultiheadSelfAttention (row-local head-mixing variant), MI355X / gfx950.
// Pipeline: fp32->bf16 cast | bf16 MFMA GEMM1 (qkv) | per-row 16x16 softmax
//           with fused transpose-scatter | bf16 MFMA GEMM2 -> fp32 out.
// ---------------------------------------------------------------------------

typedef __bf16 bf16x8 __attribute__((ext_vector_type(8)));
typedef float  f32x4  __attribute__((ext_vector_type(4)));

typedef __attribute__((address_space(3))) void       lds_void;
typedef const __attribute__((address_space(1))) void gbl_void;

__device__ __forceinline__ float b2f(unsigned short u) {
    union { unsigned int i; float f; } c; c.i = ((unsigned int)u) << 16; return c.f;
}
__device__ __forceinline__ unsigned short f2b(float f) {
    unsigned int u = __builtin_bit_cast(unsigned int, f);
    return (unsigned short)((u + 0x7FFFu + ((u >> 16) & 1u)) >> 16);  // RNE
}
__device__ __forceinline__ unsigned int pack2(float a, float b) {
    return (unsigned int)f2b(a) | ((unsigned int)f2b(b) << 16);
}
__device__ __forceinline__ void unpack8(uint4 u, float* f) {
    unsigned int w[4] = {u.x, u.y, u.z, u.w};
#pragma unroll
    for (int a = 0; a < 4; ++a) {
        union { unsigned int i; float f; } lo, hi;
        lo.i = w[a] << 16;
        hi.i = w[a] & 0xFFFF0000u;
        f[a * 2]     = lo.f;
        f[a * 2 + 1] = hi.f;
    }
}

// ------------------------------ fp32 -> bf16 -------------------------------
__global__ __launch_bounds__(256) void cvt_f32_bf16(const float* __restrict__ in,
                                                    unsigned short* __restrict__ out,
                                                    int n4) {
    int i = blockIdx.x * 256 + threadIdx.x;
    if (i >= n4) return;
    float4 f = reinterpret_cast<const float4*>(in)[i];
    ushort4 u;
    u.x = f2b(f.x); u.y = f2b(f.y); u.z = f2b(f.z); u.w = f2b(f.w);
    reinterpret_cast<ushort4*>(out)[i] = u;
}

// --------------------------- bf16 NT GEMM (m97) ----------------------------
// C[m,n] = sum_k A[m,k] * B[n,k].  A: MxK row-major, B: NxK row-major (bf16
// bit patterns as ushort).  128x128 block tile, BK=64, 4 waves in 2x2, each
// wave 4x4 MFMA 16x16x32 tiles.  global_load_lds width=16 staging.
__device__ __forceinline__ void store_c(float* C, long idx, float v)          { C[idx] = v; }
__device__ __forceinline__ void store_c(unsigned short* C, long idx, float v) { C[idx] = f2b(v); }

template <typename CT>
__global__ __launch_bounds__(256) void gemm_bt(const unsigned short* __restrict__ A,
                                               const unsigned short* __restrict__ B,
                                               CT* __restrict__ C,
                                               int M, int N, int K) {
    __shared__ __align__(16) unsigned short As[128 * 64];
    __shared__ __align__(16) unsigned short Bs[128 * 64];

    const int tid  = threadIdx.x;
    const int lane = tid & 63;
    const int wave = tid >> 6;
    const long bm  = blockIdx.y;
    const long bn  = blockIdx.x;
    const int wm   = (wave >> 1) * 64;
    const int wn   = (wave & 1) * 64;

    f32x4 acc[4][4] = {};

    const unsigned short* Ab = A + bm * 128 * (long)K;
    const unsigned short* Bb = B + bn * 128 * (long)K;

    const int srow = tid >> 3;        // staging: 16B chunk per thread per round
    const int scol = (tid & 7) * 8;

    for (int k0 = 0; k0 < K; k0 += 64) {
#pragma unroll
        for (int r = 0; r < 4; ++r) {
            const int row = r * 32 + srow;
            // LDS dest: wave-uniform base; HW scatters lane*16B.
            __builtin_amdgcn_global_load_lds(
                (gbl_void*)(Ab + (long)row * K + k0 + scol),
                (lds_void*)(As + (r * 256 + wave * 64) * 8), 16, 0, 0);
        }
#pragma unroll
        for (int r = 0; r < 4; ++r) {
            const int row = r * 32 + srow;
            __builtin_amdgcn_global_load_lds(
                (gbl_void*)(Bb + (long)row * K + k0 + scol),
                (lds_void*)(Bs + (r * 256 + wave * 64) * 8), 16, 0, 0);
        }
        __syncthreads();

#pragma unroll
        for (int kk = 0; kk < 64; kk += 32) {
            const int lcol = kk + ((lane >> 4) << 3);
            bf16x8 af[4], bfr[4];
#pragma unroll
            for (int i = 0; i < 4; ++i) {
                af[i]  = *reinterpret_cast<const bf16x8*>(As + (wm + i * 16 + (lane & 15)) * 64 + lcol);
                bfr[i] = *reinterpret_cast<const bf16x8*>(Bs + (wn + i * 16 + (lane & 15)) * 64 + lcol);
            }
#pragma unroll
            for (int i = 0; i < 4; ++i)
#pragma unroll
                for (int j = 0; j < 4; ++j)
                    acc[i][j] = __builtin_amdgcn_mfma_f32_16x16x32_bf16(af[i], bfr[j], acc[i][j], 0, 0, 0);
        }
        __syncthreads();
    }

    // Epilogue.  C/D layout (verified m89/m91): col = lane&15, row = (lane>>4)*4 + reg.
    const long mrow0 = bm * 128 + wm + ((lane >> 4) << 2);
    const long ncol0 = bn * 128 + wn + (lane & 15);
#pragma unroll
    for (int i = 0; i < 4; ++i)
#pragma unroll
        for (int j = 0; j < 4; ++j)
#pragma unroll
            for (int r = 0; r < 4; ++r)
                store_c(C, (mrow0 + i * 16 + r) * (long)N + ncol0 + j * 16, acc[i][j][r]);
}

// ------------------- per-row head attention + scatter ----------------------
// qkv row m=(b,t): q=e[0,1024), k=e[1024,2048), v=e[2048,3072); h=e/64%16.
// scores[i][j] = 0.125 * dot64(q_i, k_j); softmax over j; out[i][s]=sum_j a*v.
// Scatter: out[b,t,h,s] -> out3[b, h*128 + t/16, 64*(t%16) + s].
__global__ __launch_bounds__(256) void attn_rowlocal(const unsigned short* __restrict__ qkv,
                                                     unsigned short* __restrict__ out3) {
    __shared__ __align__(16) unsigned short rows[4][3072];   // 24 KB
    __shared__ float attnS[4][16][16];                       // 4 KB

    const int tid  = threadIdx.x;
    const int lane = tid & 63;
    const int wave = tid >> 6;
    const int m0   = blockIdx.x * 4;

    {   // cooperative load of 4 qkv rows (1536 x 16B)
        const uint4* src = reinterpret_cast<const uint4*>(qkv + (long)m0 * 3072);
        uint4* dst = reinterpret_cast<uint4*>(&rows[0][0]);
#pragma unroll
        for (int c = 0; c < 6; ++c) dst[c * 256 + tid] = src[c * 256 + tid];
    }
    __syncthreads();

    const int m = m0 + wave;
    const int b = m >> 11;
    const int t = m & 2047;
    const unsigned short* q = rows[wave];
    const unsigned short* k = q + 1024;
    const unsigned short* v = q + 2048;

    // scores: lane handles i = lane&15, j in [(lane>>4)*4, +4)
    const int i  = lane & 15;
    const int j0 = (lane >> 4) << 2;
    float sc[4] = {0.f, 0.f, 0.f, 0.f};
#pragma unroll
    for (int dc = 0; dc < 64; dc += 8) {
        uint4 qu = *reinterpret_cast<const uint4*>(q + i * 64 + dc);
        float qf[8];
        unpack8(qu, qf);
#pragma unroll
        for (int jj = 0; jj < 4; ++jj) {
            uint4 ku = *reinterpret_cast<const uint4*>(k + (j0 + jj) * 64 + dc);
            float kf[8];
            unpack8(ku, kf);
#pragma unroll
            for (int d = 0; d < 8; ++d) sc[jj] += qf[d] * kf[d];
        }
    }
#pragma unroll
    for (int jj = 0; jj < 4; ++jj) sc[jj] *= 0.125f;

    // softmax over j: reduce across lanes {i, i+16, i+32, i+48}
    float mx = fmaxf(fmaxf(sc[0], sc[1]), fmaxf(sc[2], sc[3]));
    mx = fmaxf(mx, __shfl_xor(mx, 16));
    mx = fmaxf(mx, __shfl_xor(mx, 32));
    float sum = 0.f;
#pragma unroll
    for (int jj = 0; jj < 4; ++jj) { sc[jj] = __expf(sc[jj] - mx); sum += sc[jj]; }
    sum += __shfl_xor(sum, 16);
    sum += __shfl_xor(sum, 32);
    const float inv = 1.0f / sum;
#pragma unroll
    for (int jj = 0; jj < 4; ++jj) attnS[wave][i][j0 + jj] = sc[jj] * inv;
    __syncthreads();

    // out: lane handles head oi = lane>>2, s chunk s0 = (lane&3)*16
    const int oi = lane >> 2;
    const int s0 = (lane & 3) << 4;
    float o[16];
#pragma unroll
    for (int s = 0; s < 16; ++s) o[s] = 0.f;
#pragma unroll
    for (int j = 0; j < 16; ++j) {
        const float a = attnS[wave][oi][j];
        const unsigned short* vp = v + j * 64 + s0;
        uint4 v0 = *reinterpret_cast<const uint4*>(vp);
        uint4 v1 = *reinterpret_cast<const uint4*>(vp + 8);
        float vf[16];
        unpack8(v0, vf);
        unpack8(v1, vf + 8);
#pragma unroll
        for (int s = 0; s < 16; ++s) o[s] += a * vf[s];
    }

    uint4 r0, r1;
    r0.x = pack2(o[0],  o[1]);  r0.y = pack2(o[2],  o[3]);
    r0.z = pack2(o[4],  o[5]);  r0.w = pack2(o[6],  o[7]);
    r1.x = pack2(o[8],  o[9]);  r1.y = pack2(o[10], o[11]);
    r1.z = pack2(o[12], o[13]); r1.w = pack2(o[14], o[15]);

    const long base = (long)b * (2048 * 1024)
                    + (long)(oi * 128 + (t >> 4)) * 1024
                    + 64 * (t & 15) + s0;
    *reinterpret_cast<uint4*>(out3 + base)     = r0;
    *reinterpret_cast<uint4*>(out3 + base + 8) = r1;
}

// ------------------------------- launcher ----------------------------------
extern "C" void kernel_launch(void* const* d_in, const int* in_sizes, int n_in,
                              void* d_out, int out_size, void* d_ws, size_t ws_size,
                              hipStream_t stream) {
    const float* x     = (const float*)d_in[0];   // (4,2048,1024)
    const float* Wqkv  = (const float*)d_in[1];   // (3072,1024)
    const float* Wproj = (const float*)d_in[2];   // (1024,1024)
    float* out = (float*)d_out;                   // (4,2048,1024) fp32

    char* ws = (char*)d_ws;
    unsigned short* xb     = (unsigned short*)(ws);               // 16.0 MiB
    unsigned short* wqkvb  = (unsigned short*)(ws + 16777216);    //  6.0 MiB
    unsigned short* wprojb = (unsigned short*)(ws + 23068672);    //  2.0 MiB
    unsigned short* qkvb   = (unsigned short*)(ws + 25165824);    // 48.0 MiB
    unsigned short* out3b  = (unsigned short*)(ws + 75497472);    // 16.0 MiB
    // total ws use: 92,274,688 bytes

    cvt_f32_bf16<<<dim3(8192), dim3(256), 0, stream>>>(x,     xb,     2097152);
    cvt_f32_bf16<<<dim3(3072), dim3(256), 0, stream>>>(Wqkv,  wqkvb,   786432);
    cvt_f32_bf16<<<dim3(1024), dim3(256), 0, stream>>>(Wproj, wprojb,  262144);

    // qkv = x @ Wqkv^T : M=8192, N=3072, K=1024
    gemm_bt<unsigned short><<<dim3(24, 64), dim3(256), 0, stream>>>(
        xb, wqkvb, qkvb, 8192, 3072, 1024);

    attn_rowlocal<<<dim3(2048), dim3(256), 0, stream>>>(qkvb, out3b);

    // out = out3 @ Wproj^T : M=8192, N=1024, K=1024
    gemm_bt<float><<<dim3(8, 64), dim3(256), 0, stream>>>(
        out3b, wprojb, out, 8192, 1024, 1024);
}

// Round 2
// 206.817 us; speedup vs baseline: 1.0916x; 1.0916x over previous
//
#include <hip/hip_runtime.h>

// ---------------------------------------------------------------------------
// MultiheadSelfAttention (row-local head-mixing variant), MI355X / gfx950.
// Round 2: XOR bank-swizzled LDS (conflict-free frag reads), 32x32x16 MFMA,
// GEMM2 retiled to 128x64 (4 blocks/CU), swizzled attention LDS.
// ---------------------------------------------------------------------------

typedef __bf16 bf16x8 __attribute__((ext_vector_type(8)));
typedef float  f32x16 __attribute__((ext_vector_type(16)));

typedef __attribute__((address_space(3))) void       lds_void;
typedef const __attribute__((address_space(1))) void gbl_void;

__device__ __forceinline__ unsigned short f2b(float f) {
    unsigned int u = __builtin_bit_cast(unsigned int, f);
    return (unsigned short)((u + 0x7FFFu + ((u >> 16) & 1u)) >> 16);  // RNE
}
__device__ __forceinline__ unsigned int pack2(float a, float b) {
    return (unsigned int)f2b(a) | ((unsigned int)f2b(b) << 16);
}
__device__ __forceinline__ void unpack8(uint4 u, float* f) {
    unsigned int w[4] = {u.x, u.y, u.z, u.w};
#pragma unroll
    for (int a = 0; a < 4; ++a) {
        union { unsigned int i; float f; } lo, hi;
        lo.i = w[a] << 16;
        hi.i = w[a] & 0xFFFF0000u;
        f[a * 2]     = lo.f;
        f[a * 2 + 1] = hi.f;
    }
}

// ------------------------------ fp32 -> bf16 -------------------------------
__global__ __launch_bounds__(256) void cvt_f32_bf16(const float* __restrict__ in,
                                                    unsigned short* __restrict__ out,
                                                    int n4) {
    int i = blockIdx.x * 256 + threadIdx.x;
    if (i >= n4) return;
    float4 f = reinterpret_cast<const float4*>(in)[i];
    ushort4 u;
    u.x = f2b(f.x); u.y = f2b(f.y); u.z = f2b(f.z); u.w = f2b(f.w);
    reinterpret_cast<ushort4*>(out)[i] = u;
}

// --------------------------- bf16 NT GEMM ----------------------------------
// C[m,n] = sum_k A[m,k]*B[n,k].  A: MxK rm, B: NxK rm (bf16 bits as ushort).
// Block tile 128xBN, BK=64.  4 waves 2x2; wave tile 64x(BN/2) as 2xNT tiles
// of 32x32x16 MFMA.  LDS rows are 8 chunks of 16B, chunk c of row r stored at
// slot c^(r&7) -> conflict-free ds_read_b128 AND conflict-free staging.
__device__ __forceinline__ void store_c(float* C, long idx, float v)          { C[idx] = v; }
__device__ __forceinline__ void store_c(unsigned short* C, long idx, float v) { C[idx] = f2b(v); }

template <int BN, typename CT>
__global__ __launch_bounds__(256) void gemm_bt(const unsigned short* __restrict__ A,
                                               const unsigned short* __restrict__ B,
                                               CT* __restrict__ C,
                                               int M, int N, int K) {
    constexpr int NT = BN / 64;                     // 32-col j-tiles per wave
    __shared__ __align__(16) unsigned short As[128 * 64];
    __shared__ __align__(16) unsigned short Bs[BN * 64];

    const int tid  = threadIdx.x;
    const int lane = tid & 63;
    const int wave = tid >> 6;
    const long bm  = blockIdx.y;
    const long bn  = blockIdx.x;
    const int wm   = (wave >> 1) * 64;
    const int wn   = (wave & 1) * (BN / 2);

    f32x16 acc[2][NT] = {};

    const unsigned short* Ab = A + bm * 128 * (long)K;
    const unsigned short* Bb = B + bn * BN * (long)K;

    const int srow  = tid >> 3;                        // row within 32-row group
    const int sgcol = ((tid & 7) ^ (srow & 7)) << 3;   // swizzled SOURCE chunk

    for (int k0 = 0; k0 < K; k0 += 64) {
#pragma unroll
        for (int r = 0; r < 4; ++r)
            __builtin_amdgcn_global_load_lds(
                (gbl_void*)(Ab + (long)(r * 32 + srow) * K + k0 + sgcol),
                (lds_void*)(As + (r * 256 + wave * 64) * 8), 16, 0, 0);
#pragma unroll
        for (int r = 0; r < BN / 32; ++r)
            __builtin_amdgcn_global_load_lds(
                (gbl_void*)(Bb + (long)(r * 32 + srow) * K + k0 + sgcol),
                (lds_void*)(Bs + (r * 256 + wave * 64) * 8), 16, 0, 0);
        __syncthreads();

        const int arow = lane & 31;
        const int kh   = lane >> 5;                    // k-half: k = kh*8 + j
#pragma unroll
        for (int kk = 0; kk < 4; ++kk) {               // 4 x K=16
            const int c  = kk * 2 + kh;                // logical chunk 0..7
            const int sw = (c ^ (lane & 7)) << 3;      // swizzled read offset
            bf16x8 af[2], bfr[NT];
#pragma unroll
            for (int i = 0; i < 2; ++i)
                af[i] = *reinterpret_cast<const bf16x8*>(As + (wm + i * 32 + arow) * 64 + sw);
#pragma unroll
            for (int j = 0; j < NT; ++j)
                bfr[j] = *reinterpret_cast<const bf16x8*>(Bs + (wn + j * 32 + arow) * 64 + sw);
#pragma unroll
            for (int i = 0; i < 2; ++i)
#pragma unroll
                for (int j = 0; j < NT; ++j)
                    acc[i][j] = __builtin_amdgcn_mfma_f32_32x32x16_bf16(af[i], bfr[j], acc[i][j], 0, 0, 0);
        }
        __syncthreads();
    }

    // C/D layout (verified m74/m101): col=lane&31, row=(r&3)+8*(r>>2)+4*(lane>>5)
    const long mbase = bm * 128 + wm + ((lane >> 5) << 2);
    const long nbase = bn * BN + wn + (lane & 31);
#pragma unroll
    for (int i = 0; i < 2; ++i)
#pragma unroll
        for (int j = 0; j < NT; ++j)
#pragma unroll
            for (int r = 0; r < 16; ++r) {
                const long row = mbase + i * 32 + (r & 3) + 8 * (r >> 2);
                store_c(C, row * (long)N + nbase + j * 32, acc[i][j][r]);
            }
}

// ------------------- per-row head attention + scatter ----------------------
// qkv row m=(b,t): q=e[0,1024), k=e[1024,2048), v=e[2048,3072); h=e/64%16.
// scores[i][j]=0.125*dot64(q_i,k_j); softmax over j; out[i][s]=sum_j a*v.
// Scatter: out[b,t,h,s] -> out3[b, h*128 + t/16, 64*(t%16)+s].
// rows[] is XOR chunk-swizzled: chunk c of 64-elem vector vi at c^(vi&7).
__global__ __launch_bounds__(256) void attn_rowlocal(const unsigned short* __restrict__ qkv,
                                                     unsigned short* __restrict__ out3) {
    __shared__ __align__(16) unsigned short rows[4 * 3072];  // 24 KB, swizzled
    __shared__ float attnS[4][16][17];                       // padded

    const int tid  = threadIdx.x;
    const int lane = tid & 63;
    const int wave = tid >> 6;
    const int m0   = blockIdx.x * 4;

    {   // cooperative load: LDS slot S gets global chunk (S&~7)|((S&7)^((S>>3)&7))
        const uint4* src = reinterpret_cast<const uint4*>(qkv + (long)m0 * 3072);
        uint4* dst = reinterpret_cast<uint4*>(rows);
#pragma unroll
        for (int c = 0; c < 6; ++c) {
            const int S  = c * 256 + tid;
            const int gs = (S & ~7) | ((S & 7) ^ ((S >> 3) & 7));
            dst[S] = src[gs];
        }
    }
    __syncthreads();

    const int m = m0 + wave;
    const int b = m >> 11;
    const int t = m & 2047;
    const unsigned short* rw = rows + wave * 3072;  // 48 vectors; (wave*48)&7==0

    // scores: lane handles i = lane&15, j in [(lane>>4)*4, +4)
    const int i  = lane & 15;
    const int j0 = (lane >> 4) << 2;
    float sc[4] = {0.f, 0.f, 0.f, 0.f};
#pragma unroll
    for (int c8 = 0; c8 < 8; ++c8) {
        uint4 qu = *reinterpret_cast<const uint4*>(rw + i * 64 + ((c8 ^ (i & 7)) << 3));
        float qf[8];
        unpack8(qu, qf);
#pragma unroll
        for (int jj = 0; jj < 4; ++jj) {
            const int vi = 16 + j0 + jj;
            uint4 ku = *reinterpret_cast<const uint4*>(rw + vi * 64 + ((c8 ^ (vi & 7)) << 3));
            float kf[8];
            unpack8(ku, kf);
#pragma unroll
            for (int d = 0; d < 8; ++d) sc[jj] += qf[d] * kf[d];
        }
    }
#pragma unroll
    for (int jj = 0; jj < 4; ++jj) sc[jj] *= 0.125f;

    float mx = fmaxf(fmaxf(sc[0], sc[1]), fmaxf(sc[2], sc[3]));
    mx = fmaxf(mx, __shfl_xor(mx, 16));
    mx = fmaxf(mx, __shfl_xor(mx, 32));
    float sum = 0.f;
#pragma unroll
    for (int jj = 0; jj < 4; ++jj) { sc[jj] = __expf(sc[jj] - mx); sum += sc[jj]; }
    sum += __shfl_xor(sum, 16);
    sum += __shfl_xor(sum, 32);
    const float inv = 1.0f / sum;
#pragma unroll
    for (int jj = 0; jj < 4; ++jj) attnS[wave][i][j0 + jj] = sc[jj] * inv;
    __syncthreads();

    // out: lane handles head oi = lane>>2, s chunk s0 = (lane&3)*16
    const int oi = lane >> 2;
    const int s0 = (lane & 3) << 4;
    const int c0 = (lane & 3) << 1;
    float o[16];
#pragma unroll
    for (int s = 0; s < 16; ++s) o[s] = 0.f;
#pragma unroll
    for (int j = 0; j < 16; ++j) {
        const float a  = attnS[wave][oi][j];
        const int   vi = 32 + j;
        uint4 v0 = *reinterpret_cast<const uint4*>(rw + vi * 64 + (((c0)     ^ (vi & 7)) << 3));
        uint4 v1 = *reinterpret_cast<const uint4*>(rw + vi * 64 + (((c0 + 1) ^ (vi & 7)) << 3));
        float vf[16];
        unpack8(v0, vf);
        unpack8(v1, vf + 8);
#pragma unroll
        for (int s = 0; s < 16; ++s) o[s] += a * vf[s];
    }

    uint4 r0, r1;
    r0.x = pack2(o[0],  o[1]);  r0.y = pack2(o[2],  o[3]);
    r0.z = pack2(o[4],  o[5]);  r0.w = pack2(o[6],  o[7]);
    r1.x = pack2(o[8],  o[9]);  r1.y = pack2(o[10], o[11]);
    r1.z = pack2(o[12], o[13]); r1.w = pack2(o[14], o[15]);

    const long base = (long)b * (2048 * 1024)
                    + (long)(oi * 128 + (t >> 4)) * 1024
                    + 64 * (t & 15) + s0;
    *reinterpret_cast<uint4*>(out3 + base)     = r0;
    *reinterpret_cast<uint4*>(out3 + base + 8) = r1;
}

// ------------------------------- launcher ----------------------------------
extern "C" void kernel_launch(void* const* d_in, const int* in_sizes, int n_in,
                              void* d_out, int out_size, void* d_ws, size_t ws_size,
                              hipStream_t stream) {
    const float* x     = (const float*)d_in[0];   // (4,2048,1024)
    const float* Wqkv  = (const float*)d_in[1];   // (3072,1024)
    const float* Wproj = (const float*)d_in[2];   // (1024,1024)
    float* out = (float*)d_out;                   // (4,2048,1024) fp32

    char* ws = (char*)d_ws;
    unsigned short* xb     = (unsigned short*)(ws);               // 16.0 MiB
    unsigned short* wqkvb  = (unsigned short*)(ws + 16777216);    //  6.0 MiB
    unsigned short* wprojb = (unsigned short*)(ws + 23068672);    //  2.0 MiB
    unsigned short* qkvb   = (unsigned short*)(ws + 25165824);    // 48.0 MiB
    unsigned short* out3b  = (unsigned short*)(ws + 75497472);    // 16.0 MiB

    cvt_f32_bf16<<<dim3(8192), dim3(256), 0, stream>>>(x,     xb,     2097152);
    cvt_f32_bf16<<<dim3(3072), dim3(256), 0, stream>>>(Wqkv,  wqkvb,   786432);
    cvt_f32_bf16<<<dim3(1024), dim3(256), 0, stream>>>(Wproj, wprojb,  262144);

    // qkv = x @ Wqkv^T : M=8192, N=3072, K=1024
    gemm_bt<128, unsigned short><<<dim3(24, 64), dim3(256), 0, stream>>>(
        xb, wqkvb, qkvb, 8192, 3072, 1024);

    attn_rowlocal<<<dim3(2048), dim3(256), 0, stream>>>(qkvb, out3b);

    // out = out3 @ Wproj^T : M=8192, N=1024, K=1024  (128x64 tiles, 4 blk/CU)
    gemm_bt<64, float><<<dim3(16, 64), dim3(256), 0, stream>>>(
        out3b, wprojb, out, 8192, 1024, 1024);
}

// Round 3
// 199.104 us; speedup vs baseline: 1.1338x; 1.0387x over previous
//
#include <hip/hip_runtime.h>

// ---------------------------------------------------------------------------
// MultiheadSelfAttention (row-local head-mixing variant), MI355X / gfx950.
// Round 3: single fused cvt kernel (6->4 dispatches), GEMM2 back to BN=128
// (R1 A/B showed BN=64 cost ~5us).  GEMM1 unchanged at m97-structure plateau.
// ---------------------------------------------------------------------------

typedef __bf16 bf16x8 __attribute__((ext_vector_type(8)));
typedef float  f32x16 __attribute__((ext_vector_type(16)));

typedef __attribute__((address_space(3))) void       lds_void;
typedef const __attribute__((address_space(1))) void gbl_void;

__device__ __forceinline__ unsigned short f2b(float f) {
    unsigned int u = __builtin_bit_cast(unsigned int, f);
    return (unsigned short)((u + 0x7FFFu + ((u >> 16) & 1u)) >> 16);  // RNE
}
__device__ __forceinline__ unsigned int pack2(float a, float b) {
    return (unsigned int)f2b(a) | ((unsigned int)f2b(b) << 16);
}
__device__ __forceinline__ void unpack8(uint4 u, float* f) {
    unsigned int w[4] = {u.x, u.y, u.z, u.w};
#pragma unroll
    for (int a = 0; a < 4; ++a) {
        union { unsigned int i; float f; } lo, hi;
        lo.i = w[a] << 16;
        hi.i = w[a] & 0xFFFF0000u;
        f[a * 2]     = lo.f;
        f[a * 2 + 1] = hi.f;
    }
}

// ------------------------- fused fp32 -> bf16 cast -------------------------
// One grid covers x (2097152 f4), Wqkv (786432 f4), Wproj (262144 f4).
__global__ __launch_bounds__(256) void cvt_all(const float* __restrict__ x,
                                               const float* __restrict__ wqkv,
                                               const float* __restrict__ wproj,
                                               unsigned short* __restrict__ xb,
                                               unsigned short* __restrict__ wqkvb,
                                               unsigned short* __restrict__ wprojb) {
    int i = blockIdx.x * 256 + threadIdx.x;
    const float* src;
    unsigned short* dst;
    if (i < 2097152)      { src = x;     dst = xb;                       }
    else if (i < 2883584) { src = wqkv;  dst = wqkvb;  i -= 2097152;     }
    else                  { src = wproj; dst = wprojb; i -= 2883584;     }
    float4 f = reinterpret_cast<const float4*>(src)[i];
    ushort4 u;
    u.x = f2b(f.x); u.y = f2b(f.y); u.z = f2b(f.z); u.w = f2b(f.w);
    reinterpret_cast<ushort4*>(dst)[i] = u;
}

// --------------------------- bf16 NT GEMM ----------------------------------
// C[m,n] = sum_k A[m,k]*B[n,k].  A: MxK rm, B: NxK rm (bf16 bits as ushort).
// Block tile 128x128, BK=64.  4 waves 2x2; wave tile 64x64 as 2x2 tiles of
// 32x32x16 MFMA.  LDS rows are 8 chunks of 16B; chunk c of row r at slot
// c^(r&7) -> conflict-free ds_read_b128 and conflict-free staging.
__device__ __forceinline__ void store_c(float* C, long idx, float v)          { C[idx] = v; }
__device__ __forceinline__ void store_c(unsigned short* C, long idx, float v) { C[idx] = f2b(v); }

template <typename CT>
__global__ __launch_bounds__(256) void gemm_bt(const unsigned short* __restrict__ A,
                                               const unsigned short* __restrict__ B,
                                               CT* __restrict__ C,
                                               int M, int N, int K) {
    __shared__ __align__(16) unsigned short As[128 * 64];
    __shared__ __align__(16) unsigned short Bs[128 * 64];

    const int tid  = threadIdx.x;
    const int lane = tid & 63;
    const int wave = tid >> 6;
    const long bm  = blockIdx.y;
    const long bn  = blockIdx.x;
    const int wm   = (wave >> 1) * 64;
    const int wn   = (wave & 1) * 64;

    f32x16 acc[2][2] = {};

    const unsigned short* Ab = A + bm * 128 * (long)K;
    const unsigned short* Bb = B + bn * 128 * (long)K;

    const int srow  = tid >> 3;                        // row within 32-row group
    const int sgcol = ((tid & 7) ^ (srow & 7)) << 3;   // swizzled SOURCE chunk

    for (int k0 = 0; k0 < K; k0 += 64) {
#pragma unroll
        for (int r = 0; r < 4; ++r)
            __builtin_amdgcn_global_load_lds(
                (gbl_void*)(Ab + (long)(r * 32 + srow) * K + k0 + sgcol),
                (lds_void*)(As + (r * 256 + wave * 64) * 8), 16, 0, 0);
#pragma unroll
        for (int r = 0; r < 4; ++r)
            __builtin_amdgcn_global_load_lds(
                (gbl_void*)(Bb + (long)(r * 32 + srow) * K + k0 + sgcol),
                (lds_void*)(Bs + (r * 256 + wave * 64) * 8), 16, 0, 0);
        __syncthreads();

        const int arow = lane & 31;
        const int kh   = lane >> 5;                    // k-half: k = kh*8 + j
#pragma unroll
        for (int kk = 0; kk < 4; ++kk) {               // 4 x K=16
            const int c  = kk * 2 + kh;                // logical chunk 0..7
            const int sw = (c ^ (lane & 7)) << 3;      // swizzled read offset
            bf16x8 af[2], bfr[2];
#pragma unroll
            for (int i = 0; i < 2; ++i)
                af[i] = *reinterpret_cast<const bf16x8*>(As + (wm + i * 32 + arow) * 64 + sw);
#pragma unroll
            for (int j = 0; j < 2; ++j)
                bfr[j] = *reinterpret_cast<const bf16x8*>(Bs + (wn + j * 32 + arow) * 64 + sw);
#pragma unroll
            for (int i = 0; i < 2; ++i)
#pragma unroll
                for (int j = 0; j < 2; ++j)
                    acc[i][j] = __builtin_amdgcn_mfma_f32_32x32x16_bf16(af[i], bfr[j], acc[i][j], 0, 0, 0);
        }
        __syncthreads();
    }

    // C/D layout (verified m74/m101): col=lane&31, row=(r&3)+8*(r>>2)+4*(lane>>5)
    const long mbase = bm * 128 + wm + ((lane >> 5) << 2);
    const long nbase = bn * 128 + wn + (lane & 31);
#pragma unroll
    for (int i = 0; i < 2; ++i)
#pragma unroll
        for (int j = 0; j < 2; ++j)
#pragma unroll
            for (int r = 0; r < 16; ++r) {
                const long row = mbase + i * 32 + (r & 3) + 8 * (r >> 2);
                store_c(C, row * (long)N + nbase + j * 32, acc[i][j][r]);
            }
}

// ------------------- per-row head attention + scatter ----------------------
// qkv row m=(b,t): q=e[0,1024), k=e[1024,2048), v=e[2048,3072); h=e/64%16.
// scores[i][j]=0.125*dot64(q_i,k_j); softmax over j; out[i][s]=sum_j a*v.
// Scatter: out[b,t,h,s] -> out3[b, h*128 + t/16, 64*(t%16)+s].
// rows[] is XOR chunk-swizzled: chunk c of 64-elem vector vi at c^(vi&7).
__global__ __launch_bounds__(256) void attn_rowlocal(const unsigned short* __restrict__ qkv,
                                                     unsigned short* __restrict__ out3) {
    __shared__ __align__(16) unsigned short rows[4 * 3072];  // 24 KB, swizzled
    __shared__ float attnS[4][16][17];                       // padded

    const int tid  = threadIdx.x;
    const int lane = tid & 63;
    const int wave = tid >> 6;
    const int m0   = blockIdx.x * 4;

    {   // cooperative load: LDS slot S gets global chunk (S&~7)|((S&7)^((S>>3)&7))
        const uint4* src = reinterpret_cast<const uint4*>(qkv + (long)m0 * 3072);
        uint4* dst = reinterpret_cast<uint4*>(rows);
#pragma unroll
        for (int c = 0; c < 6; ++c) {
            const int S  = c * 256 + tid;
            const int gs = (S & ~7) | ((S & 7) ^ ((S >> 3) & 7));
            dst[S] = src[gs];
        }
    }
    __syncthreads();

    const int m = m0 + wave;
    const int b = m >> 11;
    const int t = m & 2047;
    const unsigned short* rw = rows + wave * 3072;  // 48 vectors; (wave*48)&7==0

    // scores: lane handles i = lane&15, j in [(lane>>4)*4, +4)
    const int i  = lane & 15;
    const int j0 = (lane >> 4) << 2;
    float sc[4] = {0.f, 0.f, 0.f, 0.f};
#pragma unroll
    for (int c8 = 0; c8 < 8; ++c8) {
        uint4 qu = *reinterpret_cast<const uint4*>(rw + i * 64 + ((c8 ^ (i & 7)) << 3));
        float qf[8];
        unpack8(qu, qf);
#pragma unroll
        for (int jj = 0; jj < 4; ++jj) {
            const int vi = 16 + j0 + jj;
            uint4 ku = *reinterpret_cast<const uint4*>(rw + vi * 64 + ((c8 ^ (vi & 7)) << 3));
            float kf[8];
            unpack8(ku, kf);
#pragma unroll
            for (int d = 0; d < 8; ++d) sc[jj] += qf[d] * kf[d];
        }
    }
#pragma unroll
    for (int jj = 0; jj < 4; ++jj) sc[jj] *= 0.125f;

    float mx = fmaxf(fmaxf(sc[0], sc[1]), fmaxf(sc[2], sc[3]));
    mx = fmaxf(mx, __shfl_xor(mx, 16));
    mx = fmaxf(mx, __shfl_xor(mx, 32));
    float sum = 0.f;
#pragma unroll
    for (int jj = 0; jj < 4; ++jj) { sc[jj] = __expf(sc[jj] - mx); sum += sc[jj]; }
    sum += __shfl_xor(sum, 16);
    sum += __shfl_xor(sum, 32);
    const float inv = 1.0f / sum;
#pragma unroll
    for (int jj = 0; jj < 4; ++jj) attnS[wave][i][j0 + jj] = sc[jj] * inv;
    __syncthreads();

    // out: lane handles head oi = lane>>2, s chunk s0 = (lane&3)*16
    const int oi = lane >> 2;
    const int s0 = (lane & 3) << 4;
    const int c0 = (lane & 3) << 1;
    float o[16];
#pragma unroll
    for (int s = 0; s < 16; ++s) o[s] = 0.f;
#pragma unroll
    for (int j = 0; j < 16; ++j) {
        const float a  = attnS[wave][oi][j];
        const int   vi = 32 + j;
        uint4 v0 = *reinterpret_cast<const uint4*>(rw + vi * 64 + (((c0)     ^ (vi & 7)) << 3));
        uint4 v1 = *reinterpret_cast<const uint4*>(rw + vi * 64 + (((c0 + 1) ^ (vi & 7)) << 3));
        float vf[16];
        unpack8(v0, vf);
        unpack8(v1, vf + 8);
#pragma unroll
        for (int s = 0; s < 16; ++s) o[s] += a * vf[s];
    }

    uint4 r0, r1;
    r0.x = pack2(o[0],  o[1]);  r0.y = pack2(o[2],  o[3]);
    r0.z = pack2(o[4],  o[5]);  r0.w = pack2(o[6],  o[7]);
    r1.x = pack2(o[8],  o[9]);  r1.y = pack2(o[10], o[11]);
    r1.z = pack2(o[12], o[13]); r1.w = pack2(o[14], o[15]);

    const long base = (long)b * (2048 * 1024)
                    + (long)(oi * 128 + (t >> 4)) * 1024
                    + 64 * (t & 15) + s0;
    *reinterpret_cast<uint4*>(out3 + base)     = r0;
    *reinterpret_cast<uint4*>(out3 + base + 8) = r1;
}

// ------------------------------- launcher ----------------------------------
extern "C" void kernel_launch(void* const* d_in, const int* in_sizes, int n_in,
                              void* d_out, int out_size, void* d_ws, size_t ws_size,
                              hipStream_t stream) {
    const float* x     = (const float*)d_in[0];   // (4,2048,1024)
    const float* Wqkv  = (const float*)d_in[1];   // (3072,1024)
    const float* Wproj = (const float*)d_in[2];   // (1024,1024)
    float* out = (float*)d_out;                   // (4,2048,1024) fp32

    char* ws = (char*)d_ws;
    unsigned short* xb     = (unsigned short*)(ws);               // 16.0 MiB
    unsigned short* wqkvb  = (unsigned short*)(ws + 16777216);    //  6.0 MiB
    unsigned short* wprojb = (unsigned short*)(ws + 23068672);    //  2.0 MiB
    unsigned short* qkvb   = (unsigned short*)(ws + 25165824);    // 48.0 MiB
    unsigned short* out3b  = (unsigned short*)(ws + 75497472);    // 16.0 MiB

    // all three fp32->bf16 casts in one dispatch (3145728 float4s)
    cvt_all<<<dim3(12288), dim3(256), 0, stream>>>(x, Wqkv, Wproj, xb, wqkvb, wprojb);

    // qkv = x @ Wqkv^T : M=8192, N=3072, K=1024
    gemm_bt<unsigned short><<<dim3(24, 64), dim3(256), 0, stream>>>(
        xb, wqkvb, qkvb, 8192, 3072, 1024);

    attn_rowlocal<<<dim3(2048), dim3(256), 0, stream>>>(qkvb, out3b);

    // out = out3 @ Wproj^T : M=8192, N=1024, K=1024  (128x128 tiles)
    gemm_bt<float><<<dim3(8, 64), dim3(256), 0, stream>>>(
        out3b, wprojb, out, 8192, 1024, 1024);
}